// Round 3
// baseline (109.598 us; speedup 1.0000x reference)
//
#include <hip/hip_runtime.h>
#include <hip/hip_bf16.h>

#define LL 512
#define HH 128
#define NBATCH 2
#define NT 32
#define NOFF (NT*(NT-1)/2)   // 496 ordered pairs ti<tj

typedef float f32x4 __attribute__((ext_vector_type(4)));
typedef short s16x8 __attribute__((ext_vector_type(8)));
typedef unsigned int u32x4 __attribute__((ext_vector_type(4)));

__device__ __forceinline__ unsigned short f2bfu(float f){
  __hip_bfloat16 h = __float2bfloat16(f);
  return __builtin_bit_cast(unsigned short, h);
}
// max of two packed-bf16 words (both inputs bf16-valued -> exact)
__device__ __forceinline__ unsigned int bmax2(unsigned int a, unsigned int b){
  float lo = fmaxf(__uint_as_float(a << 16), __uint_as_float(b << 16));
  float hi = fmaxf(__uint_as_float(a & 0xFFFF0000u), __uint_as_float(b & 0xFFFF0000u));
  return __float_as_uint(hi) | (__float_as_uint(lo) >> 16);
}
// max3(packed-bf16 word, gmax half0 pair, gmax half1 pair) with RN pack
__device__ __forceinline__ unsigned int fold3(unsigned int p, float gl, float gh,
                                              float g2l, float g2h){
  float lo = fmaxf(fmaxf(__uint_as_float(p << 16), gl), g2l);
  float hi = fmaxf(fmaxf(__uint_as_float(p & 0xFFFF0000u), gh), g2h);
  unsigned int lor = (__float_as_uint(lo) + 0x8000u) >> 16;
  unsigned int hir = (__float_as_uint(hi) + 0x8000u) & 0xFFFF0000u;
  return hir | lor;
}
__device__ __forceinline__ float gelu_f(float v){
  float inner = v * fmaf(0.044715f, v*v, 1.0f);
  float e = __expf(1.5957691216f * inner);
  float s = __fdividef(1.0f, e + 1.0f);
  return fmaf(-v, s, v);
}
__device__ __forceinline__ f32x4 gelu4(f32x4 v){
  f32x4 r;
  #pragma unroll
  for (int i=0;i<4;++i) r[i] = gelu_f(v[i]);
  return r;
}

// ---- fused prep: t1/t2 (blocks 0..1023), bmax (..1087), Wcb bf16 (..1215) ----
__global__ void prep_kernel(const float* __restrict__ x, const float* __restrict__ y,
                            const float* __restrict__ W, const float* __restrict__ bias,
                            float* __restrict__ t1, float* __restrict__ t2,
                            float* __restrict__ bmax, short* __restrict__ Wcb){
  int blk = blockIdx.x, tid = threadIdx.x;
  if (blk < NBATCH*LL){
    int b = blk >> 9, l = blk & (LL-1);
    __shared__ float xs[HH], ys[HH];
    size_t base = ((size_t)b*LL + l)*HH;
    xs[tid] = x[base + tid];
    ys[tid] = y[base + tid];
    __syncthreads();
    const float4* wr1 = (const float4*)(W + (size_t)tid*384);
    const float4* wr2 = (const float4*)(W + (size_t)tid*384 + 128);
    const float4* xs4 = (const float4*)xs;
    const float4* ys4 = (const float4*)ys;
    float s1 = 0.f, s2 = 0.f;
    #pragma unroll
    for (int q=0;q<32;++q){
      float4 a = xs4[q], w = wr1[q];
      s1 = fmaf(a.x,w.x, fmaf(a.y,w.y, fmaf(a.z,w.z, fmaf(a.w,w.w, s1))));
      float4 c = ys4[q], w2 = wr2[q];
      s2 = fmaf(c.x,w2.x, fmaf(c.y,w2.y, fmaf(c.z,w2.z, fmaf(c.w,w2.w, s2))));
    }
    t1[base + tid] = s1 + bias[tid];
    t2[base + tid] = s2;
  } else if (blk < NBATCH*LL + NBATCH*NT){
    int e = blk - NBATCH*LL;
    int b = e >> 5, t = e & 31;
    float m = -INFINITY;
    #pragma unroll
    for (int r=0;r<16;++r) m = fmaxf(m, x[((size_t)b*LL + t*16 + r)*HH + tid]);
    bmax[(size_t)e*HH + tid] = m;
  } else {
    int g = blk - (NBATCH*LL + NBATCH*NT);
    Wcb[g*HH + tid] = (short)f2bfu(W[(size_t)g*384 + 256 + tid]);
  }
}

// ---- main: blocks 0..495 = off-diag pair (ti<tj); 496..527 = diagonal tile ----
__global__ __launch_bounds__(512, 4) void ctx_kernel(
    const float* __restrict__ x, const float* __restrict__ t1,
    const float* __restrict__ t2, const float* __restrict__ bmax,
    const short* __restrict__ Wcb, float* __restrict__ out)
{
  __shared__ __align__(16) unsigned int shbuf[5*16*64];  // 20 KB, word layout [row][64]
  const int tid = threadIdx.x;
  const int b = blockIdx.y;
  const int w = tid >> 6, l = tid & 63, l16 = l & 15, lhi = l >> 4;
  const int g0 = w*16 + lhi*4;

  s16x8 wcf[4];
  #pragma unroll
  for (int kb=0;kb<4;++kb)
    wcf[kb] = *(const s16x8*)(Wcb + (size_t)(w*16 + l16)*HH + kb*32 + lhi*8);

  if (blockIdx.x < NOFF) {
    // ================= off-diagonal pair =================
    int ti = 0, tj;
    { int rem = blockIdx.x;
      while (rem >= NT-1-ti){ rem -= NT-1-ti; ++ti; }
      tj = ti + 1 + rem; }

    unsigned short* sfxU = (unsigned short*)shbuf;            // [16][128] bf16, swizzled
    unsigned short* pfxU = (unsigned short*)(shbuf + 1024);   // [16][128]
    float* gmaxS = (float*)(shbuf + 2048);                    // [2][128]

    { // phase A: scans (one write barrier total)
      int role = tid >> 7, h = tid & 127;
      if (role == 0){
        const float* xp = x + ((size_t)b*LL + ti*16)*HH + h;
        float v[16];
        #pragma unroll
        for (int r=0;r<16;++r) v[r] = xp[(size_t)r*HH];
        float run = -INFINITY;
        #pragma unroll
        for (int r=15;r>=0;--r){ run = fmaxf(run, v[r]);
          sfxU[r*HH + (h ^ ((r&7)<<3))] = f2bfu(run); }
      } else if (role == 1){
        const float* xp = x + ((size_t)b*LL + tj*16)*HH + h;
        float v[16];
        #pragma unroll
        for (int r=0;r<16;++r) v[r] = xp[(size_t)r*HH];
        float run = -INFINITY;
        #pragma unroll
        for (int r=0;r<16;++r){ run = fmaxf(run, v[r]);
          pfxU[r*HH + (h ^ ((r&7)<<3))] = f2bfu(run); }
      } else {
        int half = role - 2;
        float g = -INFINITY;
        for (int t = ti+1+half; t < tj; t += 2)
          g = fmaxf(g, bmax[((size_t)b*NT + t)*HH + h]);
        gmaxS[half*HH + h] = g;
      }
    }
    __syncthreads();

    // fold gmax into this lane's pfx row (packed bf16 words, RN)
    unsigned int pfxg[16];
    const unsigned int* pfxW = shbuf + 1024;
    #pragma unroll
    for (int kb=0;kb<4;++kb){
      int h0 = kb*32 + lhi*8;
      int wd0 = (h0 >> 1) ^ ((l16&7)<<2);
      u32x4 u = *(const u32x4*)&pfxW[l16*64 + wd0];
      float4 ga = *(const float4*)&gmaxS[h0];
      float4 gb = *(const float4*)&gmaxS[h0+4];
      float4 gc = *(const float4*)&gmaxS[HH + h0];
      float4 gd = *(const float4*)&gmaxS[HH + h0+4];
      pfxg[kb*4+0] = fold3(u[0], ga.x, ga.y, gc.x, gc.y);
      pfxg[kb*4+1] = fold3(u[1], ga.z, ga.w, gc.z, gc.w);
      pfxg[kb*4+2] = fold3(u[2], gb.x, gb.y, gd.x, gd.y);
      pfxg[kb*4+3] = fold3(u[3], gb.z, gb.w, gd.z, gd.w);
    }

    const size_t qoff = ((size_t)b*LL + tj*16 + l16)*HH + g0;
    f32x4 t1j = *(const f32x4*)(t1 + qoff);
    f32x4 t2j = *(const f32x4*)(t2 + qoff);
    const float* t1ip = t1 + ((size_t)b*LL + ti*16)*HH + g0;
    const float* t2ip = t2 + ((size_t)b*LL + ti*16)*HH + g0;
    float* o1base = out + (((size_t)(b*LL + ti*16))*LL + tj*16 + l16)*HH + g0;
    float* o2base = out + (((size_t)(b*LL + tj*16 + l16))*LL + ti*16)*HH + g0;
    const unsigned int* sfxW = shbuf;

    #pragma unroll
    for (int pt=0; pt<16; ++pt){
      f32x4 acc = (f32x4){0.f,0.f,0.f,0.f};
      #pragma unroll
      for (int kb=0;kb<4;++kb){
        int wd0 = ((kb*32 + lhi*8) >> 1) ^ ((pt&7)<<2);
        u32x4 s = *(const u32x4*)&sfxW[pt*64 + wd0];
        unsigned int f0 = bmax2(s[0], pfxg[kb*4+0]);
        unsigned int f1 = bmax2(s[1], pfxg[kb*4+1]);
        unsigned int f2 = bmax2(s[2], pfxg[kb*4+2]);
        unsigned int f3 = bmax2(s[3], pfxg[kb*4+3]);
        u32x4 fr = (u32x4){f0,f1,f2,f3};
        acc = __builtin_amdgcn_mfma_f32_16x16x32_bf16(wcf[kb],
                __builtin_bit_cast(s16x8, fr), acc, 0, 0, 0);
      }
      f32x4 t1i = *(const f32x4*)(t1ip + (size_t)pt*HH);
      f32x4 t2i = *(const f32x4*)(t2ip + (size_t)pt*HH);
      *(f32x4*)(o1base + (size_t)pt*LL*HH) = gelu4(acc + t1i + t2j);
      *(f32x4*)(o2base + (size_t)pt*HH)    = gelu4(acc + t1j + t2i);
    }
  } else {
    // ================= diagonal tile: sparse-table range-max =================
    const int td = blockIdx.x - NOFF;
    // lvl[k][r][64 words], k=0..4: max over rows r..r+2^k-1 (clamped)
    #pragma unroll
    for (int it=0; it<2; ++it){
      int e = tid*2 + it;
      int r = e >> 6, wd = e & 63;
      float2 a = *(const float2*)(x + ((size_t)b*LL + td*16 + r)*HH + wd*2);
      unsigned int u = ((__float_as_uint(a.y) + 0x8000u) & 0xFFFF0000u)
                     | ((__float_as_uint(a.x) + 0x8000u) >> 16);
      shbuf[(0*16 + r)*64 + (wd ^ ((r&7)<<2))] = u;
    }
    __syncthreads();
    #pragma unroll
    for (int k=1;k<5;++k){
      int step = 1 << (k-1);
      unsigned int res[2]; int dst[2];
      #pragma unroll
      for (int it=0; it<2; ++it){
        int e = tid*2 + it;
        int r = e >> 6, wd = e & 63;
        int r2 = min(r + step, 15);
        unsigned int a = shbuf[((k-1)*16 + r )*64 + (wd ^ ((r &7)<<2))];
        unsigned int c = shbuf[((k-1)*16 + r2)*64 + (wd ^ ((r2&7)<<2))];
        res[it] = bmax2(a, c);
        dst[it] = (k*16 + r)*64 + (wd ^ ((r&7)<<2));
      }
      shbuf[dst[0]] = res[0];
      shbuf[dst[1]] = res[1];
      __syncthreads();
    }

    const size_t qoff = ((size_t)b*LL + td*16 + l16)*HH + g0;
    f32x4 t2j = *(const f32x4*)(t2 + qoff);
    const float* t1ip = t1 + ((size_t)b*LL + td*16)*HH + g0;
    float* obase = out + (((size_t)(b*LL + td*16))*LL + td*16 + l16)*HH + g0;

    #pragma unroll
    for (int pt=0; pt<16; ++pt){
      int a  = min(pt, l16), bb = max(pt, l16);
      int len = bb - a + 1;
      int k = 31 - __clz(len);
      int r2 = bb + 1 - (1 << k);
      f32x4 acc = (f32x4){0.f,0.f,0.f,0.f};
      #pragma unroll
      for (int kb=0;kb<4;++kb){
        int wd0 = (kb*32 + lhi*8) >> 1;
        u32x4 ua = *(const u32x4*)&shbuf[(k*16 + a )*64 + ((wd0) ^ ((a &7)<<2))];
        u32x4 ub = *(const u32x4*)&shbuf[(k*16 + r2)*64 + ((wd0) ^ ((r2&7)<<2))];
        unsigned int f0 = bmax2(ua[0], ub[0]);
        unsigned int f1 = bmax2(ua[1], ub[1]);
        unsigned int f2 = bmax2(ua[2], ub[2]);
        unsigned int f3 = bmax2(ua[3], ub[3]);
        u32x4 fr = (u32x4){f0,f1,f2,f3};
        acc = __builtin_amdgcn_mfma_f32_16x16x32_bf16(wcf[kb],
                __builtin_bit_cast(s16x8, fr), acc, 0, 0, 0);
      }
      f32x4 t1i = *(const f32x4*)(t1ip + (size_t)pt*HH);
      *(f32x4*)(obase + (size_t)pt*LL*HH) = gelu4(acc + t1i + t2j);
    }
  }
}

extern "C" void kernel_launch(void* const* d_in, const int* in_sizes, int n_in,
                              void* d_out, int out_size, void* d_ws, size_t ws_size,
                              hipStream_t stream) {
  const float* x    = (const float*)d_in[0];
  const float* y    = (const float*)d_in[1];
  const float* W    = (const float*)d_in[2];
  const float* bias = (const float*)d_in[3];
  float* out = (float*)d_out;

  float* t1 = (float*)d_ws;                           // B*L*H f32
  float* t2 = t1 + (size_t)NBATCH*LL*HH;              // B*L*H f32
  float* bmax = t2 + (size_t)NBATCH*LL*HH;            // B*NT*H f32
  short* Wcb = (short*)(bmax + (size_t)NBATCH*NT*HH); // 128*128 bf16

  prep_kernel<<<NBATCH*LL + NBATCH*NT + HH, HH, 0, stream>>>(x, y, W, bias, t1, t2, bmax, Wcb);
  ctx_kernel<<<dim3(NOFF + NT, NBATCH), 512, 0, stream>>>(x, t1, t2, bmax, Wcb, out);
}

// Round 4
// 100.559 us; speedup vs baseline: 1.0899x; 1.0899x over previous
//
#include <hip/hip_runtime.h>
#include <hip/hip_bf16.h>

#define LL 512
#define HH 128
#define NBATCH 2
#define NT 32
#define NOFF (NT*(NT-1)/2)   // 496 ordered pairs ti<tj

typedef float f32x4 __attribute__((ext_vector_type(4)));
typedef short s16x8 __attribute__((ext_vector_type(8)));
typedef unsigned int u32x4 __attribute__((ext_vector_type(4)));

__device__ __forceinline__ unsigned short f2bfu(float f){
  __hip_bfloat16 h = __float2bfloat16(f);
  return __builtin_bit_cast(unsigned short, h);
}
// max of two packed-bf16 words (both bf16-valued -> exact)
__device__ __forceinline__ unsigned int bmax2(unsigned int a, unsigned int b){
  float lo = fmaxf(__uint_as_float(a << 16), __uint_as_float(b << 16));
  float hi = fmaxf(__uint_as_float(a & 0xFFFF0000u), __uint_as_float(b & 0xFFFF0000u));
  return __float_as_uint(hi) | (__float_as_uint(lo) >> 16);
}
__device__ __forceinline__ unsigned int packbf2(float lo, float hi){
  return ((__float_as_uint(hi) + 0x8000u) & 0xFFFF0000u)
       | ((__float_as_uint(lo) + 0x8000u) >> 16);
}
__device__ __forceinline__ u32x4 bmax4(u32x4 a, u32x4 b){
  u32x4 r; r[0]=bmax2(a[0],b[0]); r[1]=bmax2(a[1],b[1]);
  r[2]=bmax2(a[2],b[2]); r[3]=bmax2(a[3],b[3]); return r;
}
__device__ __forceinline__ float gelu_f(float v){
  float inner = v * fmaf(0.044715f, v*v, 1.0f);
  float e = __expf(1.5957691216f * inner);
  float s = __fdividef(1.0f, e + 1.0f);
  return fmaf(-v, s, v);
}
__device__ __forceinline__ f32x4 gelu4(f32x4 v){
  f32x4 r;
  #pragma unroll
  for (int i=0;i<4;++i) r[i] = gelu_f(v[i]);
  return r;
}

// ---- prep: t1/t2 (1024 blocks, role-split), bmax (32), Wcb bf16 (8) ----
__global__ void prep_kernel(const float* __restrict__ x, const float* __restrict__ y,
                            const float* __restrict__ W, const float* __restrict__ bias,
                            float* __restrict__ t1, float* __restrict__ t2,
                            float* __restrict__ bmax, short* __restrict__ Wcb){
  int blk = blockIdx.x, tid = threadIdx.x;
  if (blk < NBATCH*LL){
    int b = blk >> 9, l = blk & (LL-1);
    __shared__ float xs[HH], ys[HH];
    size_t base = ((size_t)b*LL + l)*HH;
    if (tid < HH) xs[tid] = x[base + tid];
    else          ys[tid-HH] = y[base + tid - HH];
    __syncthreads();
    int role = tid >> 7, g = tid & (HH-1);
    const float4* wr = (const float4*)(W + (size_t)g*384 + role*HH);
    const float4* vs = (const float4*)(role ? ys : xs);
    float sA = 0.f, sB = 0.f;
    #pragma unroll
    for (int q=0;q<32;q+=2){
      float4 a = vs[q],   w1 = wr[q];
      sA = fmaf(a.x,w1.x, fmaf(a.y,w1.y, fmaf(a.z,w1.z, fmaf(a.w,w1.w, sA))));
      float4 c = vs[q+1], w2 = wr[q+1];
      sB = fmaf(c.x,w2.x, fmaf(c.y,w2.y, fmaf(c.z,w2.z, fmaf(c.w,w2.w, sB))));
    }
    float s = sA + sB;
    if (role == 0) t1[base + g] = s + bias[g];
    else           t2[base + g] = s;
  } else if (blk < NBATCH*LL + NBATCH*NT/2){
    int e = (blk - NBATCH*LL)*2 + (tid >> 7);
    int h = tid & (HH-1);
    int b = e >> 5, t = e & 31;
    float m = -INFINITY;
    #pragma unroll
    for (int r=0;r<16;++r) m = fmaxf(m, x[((size_t)b*LL + t*16 + r)*HH + h]);
    bmax[(size_t)e*HH + h] = m;
  } else {
    int e0 = ((blk - (NBATCH*LL + NBATCH*NT/2))*256 + tid)*8;
    #pragma unroll
    for (int i=0;i<8;++i){
      int e = e0 + i; int g = e >> 7, h = e & (HH-1);
      Wcb[e] = (short)f2bfu(W[(size_t)g*384 + 256 + h]);
    }
  }
}

// ---- main: 256 threads, one tile-pair per block; wave owns 4 i-rows ----
__global__ __launch_bounds__(256, 4) void ctx_kernel(
    const float* __restrict__ x, const float* __restrict__ t1,
    const float* __restrict__ t2, const float* __restrict__ bmax,
    const short* __restrict__ Wcb, float* __restrict__ out)
{
  __shared__ __align__(16) unsigned short shs[8192];  // 16 KB
  const int tid = threadIdx.x;
  const int b = blockIdx.y;
  const int w = tid >> 6, l = tid & 63, l16 = l & 15, lhi = l >> 4;
  const size_t bL = (size_t)b*LL;

  if (blockIdx.x < NOFF) {
    // ================= off-diagonal pair (ti < tj) =================
    int ti = 0, tj;
    { int rem = blockIdx.x;
      while (rem >= NT-1-ti){ rem -= NT-1-ti; ++ti; }
      tj = ti + 1 + rem; }

    unsigned short* sfxU = shs;          // [16][128] bf16, row-swizzled
    unsigned short* pfgU = shs + 2048;   // [16][128] pfx with gmax folded in
    { int role = tid >> 7, h = tid & (HH-1);
      if (role == 0){
        const float* xp = x + (bL + ti*16)*HH + h;
        float run = -INFINITY;
        #pragma unroll
        for (int r=15;r>=0;--r){ run = fmaxf(run, xp[r*HH]);
          sfxU[r*HH + (h ^ ((r&7)<<3))] = f2bfu(run); }
      } else {
        const float* bp = bmax + ((size_t)b*NT)*HH + h;
        float run = -INFINITY;
        for (int t=ti+1; t<tj; ++t) run = fmaxf(run, bp[t*HH]);
        const float* xp = x + (bL + tj*16)*HH + h;
        #pragma unroll
        for (int r=0;r<16;++r){ run = fmaxf(run, xp[r*HH]);
          pfgU[r*HH + (h ^ ((r&7)<<3))] = f2bfu(run); }
      }
    }
    __syncthreads();

    const int qrow = tj*16 + l16;
    const size_t qoff = (bL + qrow)*HH;

    #pragma unroll
    for (int ph=0; ph<2; ++ph){
      const int pt0 = w*4 + ph*2, pt1 = pt0 + 1;
      u32x4 fr0[4], fr1[4];
      #pragma unroll
      for (int kb=0;kb<4;++kb){
        int h0 = kb*32 + lhi*8;
        u32x4 p  = *(const u32x4*)&pfgU[l16*HH + (h0 ^ ((l16&7)<<3))];
        u32x4 s0 = *(const u32x4*)&sfxU[pt0*HH + (h0 ^ ((pt0&7)<<3))];
        u32x4 s1 = *(const u32x4*)&sfxU[pt1*HH + (h0 ^ ((pt1&7)<<3))];
        fr0[kb] = bmax4(s0, p);
        fr1[kb] = bmax4(s1, p);
      }
      const size_t i0off = (bL + ti*16 + pt0)*HH;
      const size_t i1off = (bL + ti*16 + pt1)*HH;
      const size_t o1r0 = ((bL + ti*16 + pt0)*LL + qrow)*HH;
      const size_t o1r1 = ((bL + ti*16 + pt1)*LL + qrow)*HH;
      const size_t o2r0 = ((bL + qrow)*LL + ti*16 + pt0)*HH;
      const size_t o2r1 = o2r0 + HH;

      #pragma unroll
      for (int nt=0; nt<8; ++nt){
        const int gg = nt*16 + l16;
        s16x8 wcf[4];
        #pragma unroll
        for (int kb=0;kb<4;++kb)
          wcf[kb] = *(const s16x8*)(Wcb + (size_t)gg*HH + kb*32 + lhi*8);
        f32x4 a0 = (f32x4){0.f,0.f,0.f,0.f}, a1 = a0;
        #pragma unroll
        for (int kb=0;kb<4;++kb){
          a0 = __builtin_amdgcn_mfma_f32_16x16x32_bf16(wcf[kb],
                 __builtin_bit_cast(s16x8, fr0[kb]), a0, 0, 0, 0);
          a1 = __builtin_amdgcn_mfma_f32_16x16x32_bf16(wcf[kb],
                 __builtin_bit_cast(s16x8, fr1[kb]), a1, 0, 0, 0);
        }
        const int g0 = nt*16 + lhi*4;
        f32x4 t1j = *(const f32x4*)(t1 + qoff + g0);
        f32x4 t2j = *(const f32x4*)(t2 + qoff + g0);
        f32x4 t1i0 = *(const f32x4*)(t1 + i0off + g0);
        f32x4 t2i0 = *(const f32x4*)(t2 + i0off + g0);
        f32x4 t1i1 = *(const f32x4*)(t1 + i1off + g0);
        f32x4 t2i1 = *(const f32x4*)(t2 + i1off + g0);
        *(f32x4*)(out + o1r0 + g0) = gelu4(a0 + t1i0 + t2j);
        *(f32x4*)(out + o2r0 + g0) = gelu4(a0 + t1j + t2i0);
        *(f32x4*)(out + o1r1 + g0) = gelu4(a1 + t1i1 + t2j);
        *(f32x4*)(out + o2r1 + g0) = gelu4(a1 + t1j + t2i1);
      }
    }
  } else {
    // ================= diagonal tile: 4-level sparse table =================
    const int td = blockIdx.x - NOFF;
    unsigned short* M = shs;   // [4][16][128]
    { int e = tid*8; int r = e >> 7, h0 = e & (HH-1);
      const float* xp = x + (bL + td*16 + r)*HH + h0;
      f32x4 v0 = *(const f32x4*)xp, v1 = *(const f32x4*)(xp+4);
      u32x4 pk; pk[0]=packbf2(v0[0],v0[1]); pk[1]=packbf2(v0[2],v0[3]);
      pk[2]=packbf2(v1[0],v1[1]); pk[3]=packbf2(v1[2],v1[3]);
      *(u32x4*)&M[r*HH + (h0 ^ ((r&7)<<3))] = pk;
    }
    __syncthreads();
    #pragma unroll
    for (int k=1;k<4;++k){
      int e = tid*8; int r = e >> 7, h0 = e & (HH-1);
      int r2 = min(r + (1<<(k-1)), 15);
      u32x4 a = *(const u32x4*)&M[((k-1)*16 + r )*HH + (h0 ^ ((r &7)<<3))];
      u32x4 c = *(const u32x4*)&M[((k-1)*16 + r2)*HH + (h0 ^ ((r2&7)<<3))];
      *(u32x4*)&M[(k*16 + r)*HH + (h0 ^ ((r&7)<<3))] = bmax4(a, c);
      __syncthreads();
    }

    const int qrow = td*16 + l16;
    const size_t qoff = (bL + qrow)*HH;

    #pragma unroll
    for (int ph=0; ph<2; ++ph){
      const int ptA = w*4 + ph*2;
      u32x4 fr[2][4];
      #pragma unroll
      for (int pi=0; pi<2; ++pi){
        int pt = ptA + pi;
        int a = min(pt, l16), bb = max(pt, l16);
        int len = bb - a + 1;
        int k = 31 - __clz(len); if (k > 3) k = 3;
        int r2 = bb + 1 - (1 << k);
        #pragma unroll
        for (int kb=0;kb<4;++kb){
          int h0 = kb*32 + lhi*8;
          u32x4 ua = *(const u32x4*)&M[(k*16 + a )*HH + (h0 ^ ((a &7)<<3))];
          u32x4 ub = *(const u32x4*)&M[(k*16 + r2)*HH + (h0 ^ ((r2&7)<<3))];
          fr[pi][kb] = bmax4(ua, ub);
        }
      }
      const int pt0 = ptA, pt1 = ptA + 1;
      const size_t i0off = (bL + td*16 + pt0)*HH;
      const size_t i1off = (bL + td*16 + pt1)*HH;
      const size_t o0 = ((bL + td*16 + pt0)*LL + qrow)*HH;
      const size_t o1 = ((bL + td*16 + pt1)*LL + qrow)*HH;

      #pragma unroll
      for (int nt=0; nt<8; ++nt){
        const int gg = nt*16 + l16;
        s16x8 wcf[4];
        #pragma unroll
        for (int kb=0;kb<4;++kb)
          wcf[kb] = *(const s16x8*)(Wcb + (size_t)gg*HH + kb*32 + lhi*8);
        f32x4 a0 = (f32x4){0.f,0.f,0.f,0.f}, a1 = a0;
        #pragma unroll
        for (int kb=0;kb<4;++kb){
          a0 = __builtin_amdgcn_mfma_f32_16x16x32_bf16(wcf[kb],
                 __builtin_bit_cast(s16x8, fr[0][kb]), a0, 0, 0, 0);
          a1 = __builtin_amdgcn_mfma_f32_16x16x32_bf16(wcf[kb],
                 __builtin_bit_cast(s16x8, fr[1][kb]), a1, 0, 0, 0);
        }
        const int g0 = nt*16 + lhi*4;
        f32x4 t2j = *(const f32x4*)(t2 + qoff + g0);
        f32x4 t1i0 = *(const f32x4*)(t1 + i0off + g0);
        f32x4 t1i1 = *(const f32x4*)(t1 + i1off + g0);
        *(f32x4*)(out + o0 + g0) = gelu4(a0 + t1i0 + t2j);
        *(f32x4*)(out + o1 + g0) = gelu4(a1 + t1i1 + t2j);
      }
    }
  }
}

extern "C" void kernel_launch(void* const* d_in, const int* in_sizes, int n_in,
                              void* d_out, int out_size, void* d_ws, size_t ws_size,
                              hipStream_t stream) {
  const float* x    = (const float*)d_in[0];
  const float* y    = (const float*)d_in[1];
  const float* W    = (const float*)d_in[2];
  const float* bias = (const float*)d_in[3];
  float* out = (float*)d_out;

  float* t1 = (float*)d_ws;                           // B*L*H f32
  float* t2 = t1 + (size_t)NBATCH*LL*HH;              // B*L*H f32
  float* bmax = t2 + (size_t)NBATCH*LL*HH;            // B*NT*H f32
  short* Wcb = (short*)(bmax + (size_t)NBATCH*NT*HH); // 128*128 bf16

  prep_kernel<<<NBATCH*LL + NBATCH*NT/2 + 8, 256, 0, stream>>>(x, y, W, bias, t1, t2, bmax, Wcb);
  ctx_kernel<<<dim3(NOFF + NT, NBATCH), 256, 0, stream>>>(x, t1, t2, bmax, Wcb, out);
}

// Round 5
// 98.003 us; speedup vs baseline: 1.1183x; 1.0261x over previous
//
#include <hip/hip_runtime.h>
#include <hip/hip_bf16.h>

#define LL 512
#define HH 128
#define NBATCH 2
#define NT 32
#define NOFF (NT*(NT-1)/2)   // 496 unordered pairs ti<tj

typedef float f32x4 __attribute__((ext_vector_type(4)));
typedef short s16x8 __attribute__((ext_vector_type(8)));
typedef unsigned int u32x4 __attribute__((ext_vector_type(4)));

__device__ __forceinline__ unsigned short f2bfu(float f){
  __hip_bfloat16 h = __float2bfloat16(f);
  return __builtin_bit_cast(unsigned short, h);
}
// max of two packed-bf16 words (both bf16-valued -> exact; max commutes with RN)
__device__ __forceinline__ unsigned int bmax2(unsigned int a, unsigned int b){
  float lo = fmaxf(__uint_as_float(a << 16), __uint_as_float(b << 16));
  float hi = fmaxf(__uint_as_float(a & 0xFFFF0000u), __uint_as_float(b & 0xFFFF0000u));
  return __float_as_uint(hi) | (__float_as_uint(lo) >> 16);
}
__device__ __forceinline__ unsigned int packbf2(float lo, float hi){
  return ((__float_as_uint(hi) + 0x8000u) & 0xFFFF0000u)
       | ((__float_as_uint(lo) + 0x8000u) >> 16);
}
__device__ __forceinline__ u32x4 bmax4(u32x4 a, u32x4 b){
  u32x4 r; r[0]=bmax2(a[0],b[0]); r[1]=bmax2(a[1],b[1]);
  r[2]=bmax2(a[2],b[2]); r[3]=bmax2(a[3],b[3]); return r;
}
__device__ __forceinline__ float gelu_f(float v){
  float inner = v * fmaf(0.044715f, v*v, 1.0f);
  float e = __expf(1.5957691216f * inner);
  float s = __fdividef(1.0f, e + 1.0f);
  return fmaf(-v, s, v);
}
__device__ __forceinline__ f32x4 gelu4(f32x4 v){
  f32x4 r;
  #pragma unroll
  for (int i=0;i<4;++i) r[i] = gelu_f(v[i]);
  return r;
}

// ---- prep: t1/t2 (1024 blocks, role-split), bmax (32), Wcb bf16 (8) ----
__global__ void prep_kernel(const float* __restrict__ x, const float* __restrict__ y,
                            const float* __restrict__ W, const float* __restrict__ bias,
                            float* __restrict__ t1, float* __restrict__ t2,
                            float* __restrict__ bmax, short* __restrict__ Wcb){
  int blk = blockIdx.x, tid = threadIdx.x;
  if (blk < NBATCH*LL){
    int b = blk >> 9, l = blk & (LL-1);
    __shared__ float xs[HH], ys[HH];
    size_t base = ((size_t)b*LL + l)*HH;
    if (tid < HH) xs[tid] = x[base + tid];
    else          ys[tid-HH] = y[base + tid - HH];
    __syncthreads();
    int role = tid >> 7, g = tid & (HH-1);
    const float4* wr = (const float4*)(W + (size_t)g*384 + role*HH);
    const float4* vs = (const float4*)(role ? ys : xs);
    float sA = 0.f, sB = 0.f;
    #pragma unroll
    for (int q=0;q<32;q+=2){
      float4 a = vs[q],   w1 = wr[q];
      sA = fmaf(a.x,w1.x, fmaf(a.y,w1.y, fmaf(a.z,w1.z, fmaf(a.w,w1.w, sA))));
      float4 c = vs[q+1], w2 = wr[q+1];
      sB = fmaf(c.x,w2.x, fmaf(c.y,w2.y, fmaf(c.z,w2.z, fmaf(c.w,w2.w, sB))));
    }
    float s = sA + sB;
    if (role == 0) t1[base + g] = s + bias[g];
    else           t2[base + g] = s;
  } else if (blk < NBATCH*LL + NBATCH*NT/2){
    int e = (blk - NBATCH*LL)*2 + (tid >> 7);
    int h = tid & (HH-1);
    int b = e >> 5, t = e & 31;
    float m = -INFINITY;
    #pragma unroll
    for (int r=0;r<16;++r) m = fmaxf(m, x[((size_t)b*LL + t*16 + r)*HH + h]);
    bmax[(size_t)e*HH + h] = m;
  } else {
    int e0 = ((blk - (NBATCH*LL + NBATCH*NT/2))*256 + tid)*8;
    #pragma unroll
    for (int i=0;i<8;++i){
      int e = e0 + i; int g = e >> 7, h = e & (HH-1);
      Wcb[e] = (short)f2bfu(W[(size_t)g*384 + 256 + h]);
    }
  }
}

// ---- main: 256 threads / 4 waves; unordered tile pair per block.
//      Wave-private LDS bounce turns all stores into 1 KB coalesced writes.
__global__ __launch_bounds__(256, 4) void ctx_kernel(
    const float* __restrict__ x, const float* __restrict__ t1,
    const float* __restrict__ t2, const float* __restrict__ bmax,
    const short* __restrict__ Wcb, float* __restrict__ out)
{
  __shared__ __align__(16) unsigned int shs[8192];   // 32 KB
  const int tid = threadIdx.x;
  const int b = blockIdx.y;
  const int w = tid >> 6, l = tid & 63, l16 = l & 15, lhi = l >> 4;
  const size_t bL = (size_t)b*LL;
  float* Bw = (float*)shs + w*1024;                  // 4 KB per wave: [2 pt][16 j][32 g]
  unsigned short* sIU = (unsigned short*)(shs + 4096);  // [16][128] bf16 scan (i side)
  unsigned short* sJU = sIU + 2048;                     // [16][128] bf16 scan (j side, gap folded)
  unsigned short* M   = (unsigned short*)(shs + 4096);  // diag: [4][16][128] table

  const bool isdiag = (blockIdx.x >= NOFF);
  int ti, tj;
  if (!isdiag){
    int rem = blockIdx.x; ti = 0;
    while (rem >= NT-1-ti){ rem -= NT-1-ti; ++ti; }
    tj = ti + 1 + rem;
  } else { ti = tj = blockIdx.x - NOFF; }

  if (!isdiag){
    int role = tid >> 7, h = tid & (HH-1);
    if (role == 0){
      const float* xp = x + (bL + ti*16)*HH + h;
      float run = -INFINITY;
      #pragma unroll
      for (int r=15;r>=0;--r){ run = fmaxf(run, xp[r*HH]);
        sIU[r*HH + (h ^ ((r&7)<<3))] = f2bfu(run); }
    } else {
      const float* bp = bmax + ((size_t)b*NT)*HH + h;
      float run = -INFINITY;
      for (int t=ti+1;t<tj;++t) run = fmaxf(run, bp[t*HH]);
      const float* xp = x + (bL + tj*16)*HH + h;
      #pragma unroll
      for (int r=0;r<16;++r){ run = fmaxf(run, xp[r*HH]);
        sJU[r*HH + (h ^ ((r&7)<<3))] = f2bfu(run); }
    }
    __syncthreads();
  } else {
    { int e = tid*8; int r = e >> 7, h0 = e & (HH-1);
      const float* xp = x + (bL + ti*16 + r)*HH + h0;
      f32x4 v0 = *(const f32x4*)xp, v1 = *(const f32x4*)(xp+4);
      u32x4 pk; pk[0]=packbf2(v0[0],v0[1]); pk[1]=packbf2(v0[2],v0[3]);
      pk[2]=packbf2(v1[0],v1[1]); pk[3]=packbf2(v1[2],v1[3]);
      *(u32x4*)&M[r*HH + (h0 ^ ((r&7)<<3))] = pk;
    }
    __syncthreads();
    #pragma unroll
    for (int k=1;k<4;++k){
      int e = tid*8; int r = e >> 7, h0 = e & (HH-1);
      int r2 = min(r + (1<<(k-1)), 15);
      u32x4 a = *(const u32x4*)&M[((k-1)*16 + r )*HH + (h0 ^ ((r &7)<<3))];
      u32x4 c = *(const u32x4*)&M[((k-1)*16 + r2)*HH + (h0 ^ ((r2&7)<<3))];
      *(u32x4*)&M[(k*16 + r)*HH + (h0 ^ ((r&7)<<3))] = bmax4(a, c);
      __syncthreads();
    }
  }

  const int i0 = ti*16, j0 = tj*16;

  #pragma unroll
  for (int ps=0; ps<2; ++ps){
    const int ptA = w*4 + ps*2;
    u32x4 fr[2][4];
    if (!isdiag){
      #pragma unroll
      for (int s=0;s<2;++s){
        int pt = ptA + s;
        #pragma unroll
        for (int kb=0;kb<4;++kb){
          int h0 = kb*32 + lhi*8;
          u32x4 si = *(const u32x4*)&sIU[pt*HH + (h0 ^ ((pt&7)<<3))];
          u32x4 pj = *(const u32x4*)&sJU[l16*HH + (h0 ^ ((l16&7)<<3))];
          fr[s][kb] = bmax4(si, pj);
        }
      }
    } else {
      #pragma unroll
      for (int s=0;s<2;++s){
        int pt = ptA + s;
        int a = min(pt, l16), bb2 = max(pt, l16);
        int len = bb2 - a + 1;
        int k = 31 - __clz(len); if (k>3) k=3;
        int r2 = bb2 + 1 - (1<<k);
        #pragma unroll
        for (int kb=0;kb<4;++kb){
          int h0 = kb*32 + lhi*8;
          u32x4 ua = *(const u32x4*)&M[(k*16+a )*HH + (h0 ^ ((a &7)<<3))];
          u32x4 ub = *(const u32x4*)&M[(k*16+r2)*HH + (h0 ^ ((r2&7)<<3))];
          fr[s][kb] = bmax4(ua, ub);
        }
      }
    }

    #pragma unroll
    for (int q4=0; q4<4; ++q4){
      // compute the two nt (16-g slices) of this 32-g quarter, park in LDS
      #pragma unroll
      for (int hf=0; hf<2; ++hf){
        const int nt = q4*2 + hf;
        s16x8 wcf[4];
        #pragma unroll
        for (int kb=0;kb<4;++kb)
          wcf[kb] = *(const s16x8*)(Wcb + (size_t)(nt*16+l16)*HH + kb*32 + lhi*8);
        f32x4 a0 = (f32x4){0.f,0.f,0.f,0.f}, a1 = a0;
        #pragma unroll
        for (int kb=0;kb<4;++kb){
          a0 = __builtin_amdgcn_mfma_f32_16x16x32_bf16(wcf[kb],
                 __builtin_bit_cast(s16x8, fr[0][kb]), a0, 0, 0, 0);
          a1 = __builtin_amdgcn_mfma_f32_16x16x32_bf16(wcf[kb],
                 __builtin_bit_cast(s16x8, fr[1][kb]), a1, 0, 0, 0);
        }
        const int wo = (hf*16 + lhi*4) ^ ((l16&7)<<2);
        *(f32x4*)&Bw[      l16*32 + wo] = a0;
        *(f32x4*)&Bw[512 + l16*32 + wo] = a1;
      }
      asm volatile("" ::: "memory");   // keep ds_reads below after ds_writes (same-wave DS is FIFO)

      const int gq = q4*32 + (l&7)*4;
      // o1 rows (i from ti-tile): 1 KB per store, 4 rows x 256 B segments
      #pragma unroll
      for (int s=0;s<2;++s){
        const int irow = i0 + ptA + s;
        f32x4 t1i = *(const f32x4*)(t1 + (bL+irow)*HH + gq);
        #pragma unroll
        for (int it=0; it<2; ++it){
          const int j = it*8 + (l>>3);
          f32x4 v = *(const f32x4*)&Bw[s*512 + j*32 + (((l&7)*4) ^ ((j&7)<<2))];
          f32x4 t2j = *(const f32x4*)(t2 + (bL+j0+j)*HH + gq);
          *(f32x4*)(out + ((bL+irow)*LL + j0+j)*HH + gq) = gelu4(v + t1i + t2j);
        }
      }
      if (!isdiag){
        // o2 rows (i from tj-tile): 1 KB per store, 8 x 128 B segments
        const int s2 = (l>>3)&1;
        const int icol = i0 + ptA + s2;
        f32x4 t2i = *(const f32x4*)(t2 + (bL+icol)*HH + gq);
        #pragma unroll
        for (int it=0; it<4; ++it){
          const int j = it*4 + (l>>4);
          f32x4 v = *(const f32x4*)&Bw[s2*512 + j*32 + (((l&7)*4) ^ ((j&7)<<2))];
          f32x4 t1j = *(const f32x4*)(t1 + (bL+j0+j)*HH + gq);
          *(f32x4*)(out + ((bL+j0+j)*LL + icol)*HH + gq) = gelu4(v + t1j + t2i);
        }
      }
      asm volatile("" ::: "memory");   // don't let next quarter's writes pass these reads
    }
  }
}

extern "C" void kernel_launch(void* const* d_in, const int* in_sizes, int n_in,
                              void* d_out, int out_size, void* d_ws, size_t ws_size,
                              hipStream_t stream) {
  const float* x    = (const float*)d_in[0];
  const float* y    = (const float*)d_in[1];
  const float* W    = (const float*)d_in[2];
  const float* bias = (const float*)d_in[3];
  float* out = (float*)d_out;

  float* t1 = (float*)d_ws;                           // B*L*H f32
  float* t2 = t1 + (size_t)NBATCH*LL*HH;              // B*L*H f32
  float* bmax = t2 + (size_t)NBATCH*LL*HH;            // B*NT*H f32
  short* Wcb = (short*)(bmax + (size_t)NBATCH*NT*HH); // 128*128 bf16

  prep_kernel<<<NBATCH*LL + NBATCH*NT/2 + 8, 256, 0, stream>>>(x, y, W, bias, t1, t2, bmax, Wcb);
  ctx_kernel<<<dim3(NOFF + NT, NBATCH), 256, 0, stream>>>(x, t1, t2, bmax, Wcb, out);
}